// Round 3
// baseline (197.278 us; speedup 1.0000x reference)
//
#include <hip/hip_runtime.h>
#include <stdint.h>

// ws layout:
//   [0, 32K)    pid[N]   u32
//   [32K, 64K)  dep[N]   u32 (float depth bits; positive -> monotone as u32)
//   [64K, 96K)  opa[N]   f32 (raw opacity, 0 if culled)
//   [128K, +4M) table[HW] u32 packed: (count << 24) | (sum of gaussian indices
//               & 0xFFFFFF) — zeroed by us each launch (~1 us).
//
// Gather-style output: instead of {147 MB memset + 287K scattered stores},
// ONE full-coverage coalesced write pass produces every output byte exactly
// once. count==1 pixels decode their gaussian index exactly from the packed
// sum (T=1 so alpha = raw opacity). count>1 pixels (expected ~36 pairs for
// this data: 8192 gaussians uniform over ~960x960 pixels) are written 0 and
// fixed up by a stream-ordered O(N)-scan kernel with atomicAdd.
// Index-sum overflow into the count byte needs sum >= 2^24: impossible here
// (max realistic colliders per pixel ~4, sum < 4*8192).

// ---------------------------------------------------------------------------
// Kernel A: project all N gaussians; pack (count, idx-sum) per pixel.
// ---------------------------------------------------------------------------
__global__ __launch_bounds__(256) void gs_project_kernel(
        const float* __restrict__ centers, const float* __restrict__ opac,
        const float* __restrict__ pose, const float* __restrict__ Km,
        const int* __restrict__ Hp, const int* __restrict__ Wp,
        unsigned int* __restrict__ pid_a, unsigned int* __restrict__ dep_a,
        float* __restrict__ opa_a, unsigned int* __restrict__ table, int N) {
    int i = blockIdx.x * blockDim.x + threadIdx.x;
    if (i >= N) return;
    const int H = *Hp, W = *Wp;
    float x = centers[3 * i], y = centers[3 * i + 1], zc = centers[3 * i + 2];
    float cxx = pose[0] * x + pose[1] * y + pose[2]  * zc + pose[3];
    float cyy = pose[4] * x + pose[5] * y + pose[6]  * zc + pose[7];
    float czz = pose[8] * x + pose[9] * y + pose[10] * zc + pose[11];
    bool valid = czz > 0.1f;
    float p0 = Km[0] * cxx + Km[1] * cyy + Km[2] * czz;
    float p1 = Km[3] * cxx + Km[4] * cyy + Km[5] * czz;
    float p2 = Km[6] * cxx + Km[7] * cyy + Km[8] * czz;
    float denom = valid ? p2 : 1.0f;
    int px = (int)(p0 / denom);   // trunc == numpy astype(int32)
    int py = (int)(p1 / denom);
    bool ok = valid && px >= 0 && px < W && py >= 0 && py < H;
    unsigned int pid = ok ? (unsigned int)(py * W + px) : (unsigned int)(H * W);
    pid_a[i] = pid;
    dep_a[i] = __float_as_uint(czz);     // only read when pid matches (ok)
    opa_a[i] = ok ? opac[i] : 0.0f;
    if (ok) atomicAdd(&table[pid], (1u << 24) | (unsigned int)i);
}

// ---------------------------------------------------------------------------
// Kernel B: full-coverage gather pass. 4 pixels/thread (float4 per plane).
// Writes every output element exactly once:
//   count==0 -> 0 ; count==1 -> opa[idx] * feat[idx][plane] ; count>1 -> 0
// Coalescing: consecutive threads own consecutive float4s; per wave, each
// plane gets a contiguous 1 KB store segment.
// ---------------------------------------------------------------------------
__global__ __launch_bounds__(256) void gs_gather_kernel(
        const unsigned int* __restrict__ table,
        const float* __restrict__ opa_a,
        const float* __restrict__ colors, const float* __restrict__ sem,
        float* __restrict__ out, int HW, int sem_dim) {
    const int q = blockIdx.x * blockDim.x + threadIdx.x;  // quad-pixel index
    const int nq = HW >> 2;
    if (q >= nq) return;
    const int fd = 3 + sem_dim;  // 35
    uint4 rec4 = ((const uint4*)table)[q];
    float4* dst = (float4*)out + q;  // plane stride = nq float4s

    if ((rec4.x | rec4.y | rec4.z | rec4.w) == 0u) {
        const float4 z = make_float4(0.f, 0.f, 0.f, 0.f);
        for (int pl = 0; pl < fd; ++pl) dst[(size_t)pl * nq] = z;
    } else {
        unsigned int r[4] = {rec4.x, rec4.y, rec4.z, rec4.w};
        int   idx[4];
        float a[4];
        #pragma unroll
        for (int k = 0; k < 4; ++k) {
            idx[k] = (int)(r[k] & 0xFFFFFFu);
            a[k] = ((r[k] >> 24) == 1u) ? opa_a[idx[k]] : 0.0f;  // T=1, alpha=o
        }
        for (int pl = 0; pl < fd; ++pl) {
            float v[4];
            #pragma unroll
            for (int k = 0; k < 4; ++k) {
                float f = 0.0f;
                if (a[k] != 0.0f)
                    f = (pl < 3) ? colors[3 * idx[k] + pl]
                                 : sem[sem_dim * idx[k] + (pl - 3)];
                v[k] = a[k] * f;
            }
            dst[(size_t)pl * nq] = make_float4(v[0], v[1], v[2], v[3]);
        }
    }

    // Scalar tail if HW not divisible by 4 (not hit for 1024x1024).
    if (q == 0) {
        for (int pix = nq << 2; pix < HW; ++pix) {
            unsigned int r = table[pix];
            int   id = (int)(r & 0xFFFFFFu);
            float a  = ((r >> 24) == 1u) ? opa_a[id] : 0.0f;
            for (int pl = 0; pl < fd; ++pl) {
                float f = 0.0f;
                if (a != 0.0f)
                    f = (pl < 3) ? colors[3 * id + pl]
                                 : sem[sem_dim * id + (pl - 3)];
                out[(size_t)pl * HW + pix] = a * f;
            }
        }
    }
}

// ---------------------------------------------------------------------------
// Kernel C: collision fixup. One wave per gaussian; exits unless its pixel
// has count>1. O(N) pid scan (uint4 from L2) computes
//   T_i = prod_{j: pid_j==pid_i, (dep_j, j) < (dep_i, i)} (1 - clip(o_j))
// (stable-sort tie-break via index), then atomicAdd onto the zeros kernel B
// wrote. Stream-ordered after B.
// ---------------------------------------------------------------------------
__global__ __launch_bounds__(256) void gs_collide_kernel(
        const unsigned int* __restrict__ pid_a, const unsigned int* __restrict__ dep_a,
        const float* __restrict__ opa_a, const unsigned int* __restrict__ table,
        const float* __restrict__ colors, const float* __restrict__ sem,
        float* __restrict__ out, int N, int sem_dim, int HW) {
    const int t = threadIdx.x;
    const int lane = t & 63;
    const int wave = t >> 6;
    const int i = blockIdx.x * 4 + wave;
    if (i >= N) return;

    const unsigned int pid_i = pid_a[i];
    if (pid_i >= (unsigned int)HW) return;      // culled / offscreen
    if ((table[pid_i] >> 24) <= 1u) return;     // unique: handled by gather

    const float oi = opa_a[i];
    const unsigned int di = dep_a[i];
    float prod = 1.0f;
    const uint4* p4 = (const uint4*)pid_a;
    const int nq = N >> 2;
    for (int q = lane; q < nq; q += 64) {
        uint4 p = p4[q];
        int j0 = q << 2;
        #pragma unroll
        for (int k = 0; k < 4; ++k) {
            unsigned int pj = (k == 0) ? p.x : (k == 1) ? p.y : (k == 2) ? p.z : p.w;
            int j = j0 + k;
            if (pj == pid_i && j != i) {
                unsigned int dj = dep_a[j];
                if (dj < di || (dj == di && j < i)) {
                    prod *= 1.0f - fminf(fmaxf(opa_a[j], 0.0f), 1.0f - 1e-7f);
                }
            }
        }
    }
    for (int off = 32; off > 0; off >>= 1) prod *= __shfl_xor(prod, off, 64);

    const float alpha = oi * prod;
    const int fd = 3 + sem_dim;  // 35
    if (lane < fd) {
        float f = (lane < 3) ? colors[3 * i + lane] : sem[sem_dim * i + (lane - 3)];
        atomicAdd(&out[(size_t)lane * (size_t)HW + pid_i], alpha * f);
    }
}

extern "C" void kernel_launch(void* const* d_in, const int* in_sizes, int n_in,
                              void* d_out, int out_size, void* d_ws, size_t ws_size,
                              hipStream_t stream) {
    const float* centers = (const float*)d_in[0];  // (N,3)
    const float* colors  = (const float*)d_in[1];  // (N,3)
    const float* opac    = (const float*)d_in[2];  // (N,1)
    const float* sem     = (const float*)d_in[3];  // (N,SEM_DIM)
    const float* pose    = (const float*)d_in[4];  // (4,4)
    const float* Km      = (const float*)d_in[5];  // (3,3)
    const int*   Hp      = (const int*)d_in[6];
    const int*   Wp      = (const int*)d_in[7];

    int N = in_sizes[0] / 3;        // 8192
    int sem_dim = in_sizes[3] / N;  // 32
    int fd = 3 + sem_dim;           // 35
    int HW = out_size / fd;         // 1024*1024

    char* ws = (char*)d_ws;
    unsigned int* pid_a  = (unsigned int*)(ws);
    unsigned int* dep_a  = (unsigned int*)(ws + 32 * 1024);
    float*        opa_a  = (float*)      (ws + 64 * 1024);
    unsigned int* table  = (unsigned int*)(ws + 128 * 1024);  // HW u32 packed

    // 4 MiB table zero (~1 us). NO 147 MB output memset: the gather pass
    // writes every output element exactly once.
    hipMemsetAsync(table, 0, (size_t)HW * sizeof(unsigned int), stream);

    gs_project_kernel<<<(N + 255) / 256, 256, 0, stream>>>(
        centers, opac, pose, Km, Hp, Wp, pid_a, dep_a, opa_a, table, N);

    int nq = HW >> 2;
    gs_gather_kernel<<<(nq + 255) / 256, 256, 0, stream>>>(
        table, opa_a, colors, sem, (float*)d_out, HW, sem_dim);

    gs_collide_kernel<<<(N + 3) / 4, 256, 0, stream>>>(
        pid_a, dep_a, opa_a, table, colors, sem,
        (float*)d_out, N, sem_dim, HW);
}

// Round 4
// 179.032 us; speedup vs baseline: 1.1019x; 1.1019x over previous
//
#include <hip/hip_runtime.h>
#include <stdint.h>

// ws layout:
//   [0, 32K)    pid[N]   u32
//   [32K, 64K)  dep[N]   u32 (float depth bits; positive -> monotone as u32)
//   [64K, 96K)  opa[N]   f32 (raw opacity, 0 if culled)
//   [128K, +4M) table[HW] u32 packed: (count << 24) | (sum of gaussian indices
//               & 0xFFFFFF) — zeroed by us each launch (~1 us).
//
// Gather-style output, plane-per-blockIdx.y mapping: each thread writes
// exactly ONE float4 at a streaming (memset-like) address. Round-3's
// thread-loops-over-35-planes mapping measured ~2.9 TB/s effective write BW
// (35-deep dependent store chain, 4 MiB plane hops every 1 KB); this mapping
// makes the store stream byte-identical to the fill kernel's. Table re-read
// across planes (35 x 4 MB) is L2-amortized.
// count==1 pixels decode their gaussian index exactly from the packed sum
// (T=1 so alpha = raw opacity). count>1 pixels (~36 pairs expected) get 0 and
// are fixed up by a stream-ordered O(N)-scan kernel with atomicAdd.

// ---------------------------------------------------------------------------
// Kernel A: project all N gaussians; pack (count, idx-sum) per pixel.
// ---------------------------------------------------------------------------
__global__ __launch_bounds__(256) void gs_project_kernel(
        const float* __restrict__ centers, const float* __restrict__ opac,
        const float* __restrict__ pose, const float* __restrict__ Km,
        const int* __restrict__ Hp, const int* __restrict__ Wp,
        unsigned int* __restrict__ pid_a, unsigned int* __restrict__ dep_a,
        float* __restrict__ opa_a, unsigned int* __restrict__ table, int N) {
    int i = blockIdx.x * blockDim.x + threadIdx.x;
    if (i >= N) return;
    const int H = *Hp, W = *Wp;
    float x = centers[3 * i], y = centers[3 * i + 1], zc = centers[3 * i + 2];
    float cxx = pose[0] * x + pose[1] * y + pose[2]  * zc + pose[3];
    float cyy = pose[4] * x + pose[5] * y + pose[6]  * zc + pose[7];
    float czz = pose[8] * x + pose[9] * y + pose[10] * zc + pose[11];
    bool valid = czz > 0.1f;
    float p0 = Km[0] * cxx + Km[1] * cyy + Km[2] * czz;
    float p1 = Km[3] * cxx + Km[4] * cyy + Km[5] * czz;
    float p2 = Km[6] * cxx + Km[7] * cyy + Km[8] * czz;
    float denom = valid ? p2 : 1.0f;
    int px = (int)(p0 / denom);   // trunc == numpy astype(int32)
    int py = (int)(p1 / denom);
    bool ok = valid && px >= 0 && px < W && py >= 0 && py < H;
    unsigned int pid = ok ? (unsigned int)(py * W + px) : (unsigned int)(H * W);
    pid_a[i] = pid;
    dep_a[i] = __float_as_uint(czz);     // only read when pid matches (ok)
    opa_a[i] = ok ? opac[i] : 0.0f;
    if (ok) atomicAdd(&table[pid], (1u << 24) | (unsigned int)i);
}

// ---------------------------------------------------------------------------
// Kernel B: full-coverage gather pass. blockIdx.y = plane (0..34);
// each thread: one 16 B table read (L2-hot after plane 0) + one 16 B
// streaming store. Empty quads (~99%) write pure zeros; count==1 pixels
// write opa[idx]*feat[idx][plane]; count>1 write 0 (fixed up by kernel C).
// ---------------------------------------------------------------------------
__global__ __launch_bounds__(256) void gs_gather_kernel(
        const unsigned int* __restrict__ table,
        const float* __restrict__ opa_a,
        const float* __restrict__ colors, const float* __restrict__ sem,
        float* __restrict__ out, int HW, int sem_dim) {
    const int nq = HW >> 2;
    const int q = blockIdx.x * blockDim.x + threadIdx.x;  // quad-pixel index
    const int pl = blockIdx.y;                            // plane
    if (q >= nq) return;

    uint4 rec4 = ((const uint4*)table)[q];
    float4 v = make_float4(0.f, 0.f, 0.f, 0.f);
    if ((rec4.x | rec4.y | rec4.z | rec4.w) != 0u) {
        unsigned int r[4] = {rec4.x, rec4.y, rec4.z, rec4.w};
        float vv[4];
        #pragma unroll
        for (int k = 0; k < 4; ++k) {
            float val = 0.0f;
            if ((r[k] >> 24) == 1u) {               // unique: T=1, alpha=o
                int idx = (int)(r[k] & 0xFFFFFFu);
                float a = opa_a[idx];
                float f = (pl < 3) ? colors[3 * idx + pl]
                                   : sem[sem_dim * idx + (pl - 3)];
                val = a * f;
            }
            vv[k] = val;
        }
        v = make_float4(vv[0], vv[1], vv[2], vv[3]);
    }
    ((float4*)(out + (size_t)pl * (size_t)HW))[q] = v;

    // Scalar tail if HW not divisible by 4 (not hit for 1024x1024).
    if (q == 0) {
        for (int pix = nq << 2; pix < HW; ++pix) {
            unsigned int rr = table[pix];
            float val = 0.0f;
            if ((rr >> 24) == 1u) {
                int idx = (int)(rr & 0xFFFFFFu);
                float f = (pl < 3) ? colors[3 * idx + pl]
                                   : sem[sem_dim * idx + (pl - 3)];
                val = opa_a[idx] * f;
            }
            out[(size_t)pl * (size_t)HW + pix] = val;
        }
    }
}

// ---------------------------------------------------------------------------
// Kernel C: collision fixup. One wave per gaussian; exits unless its pixel
// has count>1. O(N) pid scan (uint4 from L2) computes
//   T_i = prod_{j: pid_j==pid_i, (dep_j, j) < (dep_i, i)} (1 - clip(o_j))
// (stable-sort tie-break via index), then atomicAdd onto the zeros kernel B
// wrote. Stream-ordered after B.
// ---------------------------------------------------------------------------
__global__ __launch_bounds__(256) void gs_collide_kernel(
        const unsigned int* __restrict__ pid_a, const unsigned int* __restrict__ dep_a,
        const float* __restrict__ opa_a, const unsigned int* __restrict__ table,
        const float* __restrict__ colors, const float* __restrict__ sem,
        float* __restrict__ out, int N, int sem_dim, int HW) {
    const int t = threadIdx.x;
    const int lane = t & 63;
    const int wave = t >> 6;
    const int i = blockIdx.x * 4 + wave;
    if (i >= N) return;

    const unsigned int pid_i = pid_a[i];
    if (pid_i >= (unsigned int)HW) return;      // culled / offscreen
    if ((table[pid_i] >> 24) <= 1u) return;     // unique: handled by gather

    const float oi = opa_a[i];
    const unsigned int di = dep_a[i];
    float prod = 1.0f;
    const uint4* p4 = (const uint4*)pid_a;
    const int nq = N >> 2;
    for (int q = lane; q < nq; q += 64) {
        uint4 p = p4[q];
        int j0 = q << 2;
        #pragma unroll
        for (int k = 0; k < 4; ++k) {
            unsigned int pj = (k == 0) ? p.x : (k == 1) ? p.y : (k == 2) ? p.z : p.w;
            int j = j0 + k;
            if (pj == pid_i && j != i) {
                unsigned int dj = dep_a[j];
                if (dj < di || (dj == di && j < i)) {
                    prod *= 1.0f - fminf(fmaxf(opa_a[j], 0.0f), 1.0f - 1e-7f);
                }
            }
        }
    }
    for (int off = 32; off > 0; off >>= 1) prod *= __shfl_xor(prod, off, 64);

    const float alpha = oi * prod;
    const int fd = 3 + sem_dim;  // 35
    if (lane < fd) {
        float f = (lane < 3) ? colors[3 * i + lane] : sem[sem_dim * i + (lane - 3)];
        atomicAdd(&out[(size_t)lane * (size_t)HW + pid_i], alpha * f);
    }
}

extern "C" void kernel_launch(void* const* d_in, const int* in_sizes, int n_in,
                              void* d_out, int out_size, void* d_ws, size_t ws_size,
                              hipStream_t stream) {
    const float* centers = (const float*)d_in[0];  // (N,3)
    const float* colors  = (const float*)d_in[1];  // (N,3)
    const float* opac    = (const float*)d_in[2];  // (N,1)
    const float* sem     = (const float*)d_in[3];  // (N,SEM_DIM)
    const float* pose    = (const float*)d_in[4];  // (4,4)
    const float* Km      = (const float*)d_in[5];  // (3,3)
    const int*   Hp      = (const int*)d_in[6];
    const int*   Wp      = (const int*)d_in[7];

    int N = in_sizes[0] / 3;        // 8192
    int sem_dim = in_sizes[3] / N;  // 32
    int fd = 3 + sem_dim;           // 35
    int HW = out_size / fd;         // 1024*1024

    char* ws = (char*)d_ws;
    unsigned int* pid_a  = (unsigned int*)(ws);
    unsigned int* dep_a  = (unsigned int*)(ws + 32 * 1024);
    float*        opa_a  = (float*)      (ws + 64 * 1024);
    unsigned int* table  = (unsigned int*)(ws + 128 * 1024);  // HW u32 packed

    // 4 MiB table zero (~1 us). NO 147 MB output memset: the gather pass
    // writes every output element exactly once.
    hipMemsetAsync(table, 0, (size_t)HW * sizeof(unsigned int), stream);

    gs_project_kernel<<<(N + 255) / 256, 256, 0, stream>>>(
        centers, opac, pose, Km, Hp, Wp, pid_a, dep_a, opa_a, table, N);

    int nq = HW >> 2;
    dim3 ggrid((nq + 255) / 256, fd);
    gs_gather_kernel<<<ggrid, 256, 0, stream>>>(
        table, opa_a, colors, sem, (float*)d_out, HW, sem_dim);

    gs_collide_kernel<<<(N + 3) / 4, 256, 0, stream>>>(
        pid_a, dep_a, opa_a, table, colors, sem,
        (float*)d_out, N, sem_dim, HW);
}